// Round 6
// baseline (161.655 us; speedup 1.0000x reference)
//
#include <hip/hip_runtime.h>

// PatchMask via bulk copy + sparse zero:
//   out = x  (rocclr blit, platform's fastest stream)
//   then out[b, c, p*25 : p*25+25] = 0 for each masked unit u=idx[j], u=(c,p)
// B=128, C=128, T=5000, PATCH=25, NP=200, UNITS=25600, NMASK=2560

#define PM_B 128
#define PM_C 128
#define PM_T 5000
#define PM_PATCH 25
#define PM_NP 200                          // PM_T / PM_PATCH
#define PM_NMASK 2560
#define PM_ZERO_PER_UNIT (PM_B * PM_PATCH)          // 3200 floats per masked unit
#define PM_ZERO_TOTAL (PM_NMASK * PM_ZERO_PER_UNIT) // 8,192,000 floats

__global__ __launch_bounds__(256) void pm_zero_patches(
    const int* __restrict__ idx,
    float* __restrict__ out)
{
    unsigned n = blockIdx.x * 256u + threadIdx.x;
    if (n >= PM_ZERO_TOTAL) return;

    const unsigned j = n / PM_ZERO_PER_UNIT;        // which masked unit (magic-mul)
    const unsigned r = n - j * PM_ZERO_PER_UNIT;    // [0, 3200)
    const unsigned b = r / PM_PATCH;                // batch
    const unsigned s = r - b * PM_PATCH;            // sample within patch [0,25)

    const unsigned u = (unsigned)idx[j];            // broadcast within 25-thread group (L1/L2 hit)
    const unsigned c = u / PM_NP;
    const unsigned p = u - c * PM_NP;

    const size_t t = (size_t)p * PM_PATCH + s;
    out[((size_t)b * PM_C + c) * PM_T + t] = 0.0f;
}

extern "C" void kernel_launch(void* const* d_in, const int* in_sizes, int n_in,
                              void* d_out, int out_size, void* d_ws, size_t ws_size,
                              hipStream_t stream) {
    const float* x   = (const float*)d_in[0];
    const int*   idx = (const int*)d_in[1];
    float*       out = (float*)d_out;

    // Bulk copy: 128*128*5000 floats = 327.68 MB, runs as rocclr blit kernel.
    (void)hipMemcpyAsync(out, x, (size_t)out_size * sizeof(float),
                         hipMemcpyDeviceToDevice, stream);

    // Zero the masked patches: 8.192e6 floats = 32.77 MB of writes,
    // consecutive threads -> consecutive floats within a 100 B patch segment.
    const unsigned blocks = (PM_ZERO_TOTAL + 255u) / 256u;   // 32000
    pm_zero_patches<<<blocks, 256, 0, stream>>>(idx, out);
}

// Round 7
// 139.931 us; speedup vs baseline: 1.1552x; 1.1552x over previous
//
#include <hip/hip_runtime.h>

// PatchMask: out[b,c,t] = x[b,c,t] * um[c*NP + t/PATCH]
// um = 1.0 default, 0.0 at masked units (built by one tiny single-block kernel).
// Apply: contiguous-chunk-per-block nt stream (copy-bench shape).
// B=128, C=128, T=5000, PATCH=25, NP=200, UNITS=25600, NMASK=2560

#define PM_B 128
#define PM_C 128
#define PM_T 5000
#define PM_PATCH 25
#define PM_NP 200                      // PM_T / PM_PATCH
#define PM_UNITS (PM_C * PM_NP)        // 25600
#define PM_NMASK 2560
#define PM_F4_PER_ROW (PM_T / 4)       // 1250
#define PM_F4_TOTAL (PM_B * PM_C * PM_F4_PER_ROW)  // 20,480,000
#define PM_NBLK 2048
#define PM_CHUNK (PM_F4_TOTAL / PM_NBLK)           // 10,000 float4 per block

typedef float f32x4 __attribute__((ext_vector_type(4)));

__global__ __launch_bounds__(1024) void pm_build_mask(
    const int* __restrict__ idx, float* __restrict__ um)
{
    const unsigned tid = threadIdx.x;
    const f32x4 one = {1.0f, 1.0f, 1.0f, 1.0f};
    for (unsigned i = tid; i < PM_UNITS / 4; i += 1024u)   // 6400 f32x4
        ((f32x4*)um)[i] = one;
    __syncthreads();
    for (unsigned j = tid; j < PM_NMASK; j += 1024u)
        um[idx[j]] = 0.0f;
}

__device__ __forceinline__ void pm_one(
    unsigned i, const f32x4* __restrict__ x, const float* __restrict__ um,
    f32x4* __restrict__ out)
{
    const unsigned row = i / PM_F4_PER_ROW;            // magic-mul
    const unsigned t0  = (i - row * PM_F4_PER_ROW) * 4u;
    const float* __restrict__ um_c = um + (row & (PM_C - 1)) * PM_NP;

    f32x4 v = __builtin_nontemporal_load(x + i);

    const unsigned p0 = t0 / PM_PATCH;
    const unsigned p3 = (t0 + 3u) / PM_PATCH;
    const float m0 = um_c[p0];
    if (p0 == p3) {
        v *= m0;
    } else {
        const float m3 = um_c[p3];
        const unsigned boundary = p3 * PM_PATCH;       // first t in patch p3
        v.x *= (t0 + 0u < boundary) ? m0 : m3;
        v.y *= (t0 + 1u < boundary) ? m0 : m3;
        v.z *= (t0 + 2u < boundary) ? m0 : m3;
        v.w *= (t0 + 3u < boundary) ? m0 : m3;
    }

    __builtin_nontemporal_store(v, out + i);
}

__global__ __launch_bounds__(256) void pm_apply_mask(
    const f32x4* __restrict__ x,
    const float* __restrict__ um,
    f32x4* __restrict__ out)
{
    // Contiguous chunk per block: block walks 10,000 float4 = 156.25 KB
    // sequentially; every wave iteration advances 4 KB within the chunk.
    const unsigned base = blockIdx.x * PM_CHUNK;
    unsigned k = threadIdx.x;
    #pragma nounroll
    for (; k + 256u <= PM_CHUNK; k += 256u)            // 39 full iterations
        pm_one(base + k, x, um, out);
    if (k < PM_CHUNK)                                   // ragged 16-lane tail
        pm_one(base + k, x, um, out);
}

extern "C" void kernel_launch(void* const* d_in, const int* in_sizes, int n_in,
                              void* d_out, int out_size, void* d_ws, size_t ws_size,
                              hipStream_t stream) {
    const float* x   = (const float*)d_in[0];
    const int*   idx = (const int*)d_in[1];
    float*       out = (float*)d_out;
    float*       um  = (float*)d_ws;   // 25600 floats = 100 KiB scratch

    pm_build_mask<<<1, 1024, 0, stream>>>(idx, um);

    pm_apply_mask<<<PM_NBLK, 256, 0, stream>>>(
        (const f32x4*)x, um, (f32x4*)out);
}